// Round 9
// baseline (1091.898 us; speedup 1.0000x reference)
//
#include <hip/hip_runtime.h>
#include <hip/hip_bf16.h>

typedef __attribute__((ext_vector_type(4))) float  f4;
typedef __attribute__((ext_vector_type(8))) short  s8;
typedef __attribute__((ext_vector_type(4))) short  s4;

#define MFMA16(A,B,C) __builtin_amdgcn_mfma_f32_16x16x32_bf16((A),(B),(C),0,0,0)

// Native cast -> compiler emits v_cvt_pk_bf16_f32 for pairs (RNE).
__device__ __forceinline__ short f2bf(float f) {
  __hip_bfloat16 h = __float2bfloat16(f);
  return __builtin_bit_cast(short, h);
}

__device__ __forceinline__ f4 f4zero() { f4 z; z[0]=0.f; z[1]=0.f; z[2]=0.f; z[3]=0.f; return z; }

__device__ __forceinline__ s8 s8cat(s4 a, s4 b) {
  s8 r; r[0]=a[0]; r[1]=a[1]; r[2]=a[2]; r[3]=a[3];
       r[4]=b[0]; r[5]=b[1]; r[6]=b[2]; r[7]=b[3]; return r;
}

// Zero-cost fence: stops IR + MIR code motion across the LDS write->read handoff.
// DS pipe is in-order per wave, so no hardware wait is required for same-wave RAW.
__device__ __forceinline__ void wave_fence() {
  __builtin_amdgcn_wave_barrier();
  __builtin_amdgcn_sched_barrier(0);
}

// ---------------- prep: x/weight bf16 conversion + relative-position bias ----------------
__global__ __launch_bounds__(256) void prep_kernel(
    const float* __restrict__ x, short* __restrict__ xbf, int nx8,
    const float* __restrict__ qkv_w, const float* __restrict__ proj_w,
    const float* __restrict__ table,
    short* __restrict__ wqkv, short* __restrict__ wproj, float* __restrict__ biasf)
{
  int idx = blockIdx.x * 256 + threadIdx.x;
  if (idx < nx8) {
    const f4* src = (const f4*)(x + (size_t)idx * 8);
    f4 a = src[0], c = src[1];
    s8 v;
    v[0]=f2bf(a[0]); v[1]=f2bf(a[1]); v[2]=f2bf(a[2]); v[3]=f2bf(a[3]);
    v[4]=f2bf(c[0]); v[5]=f2bf(c[1]); v[6]=f2bf(c[2]); v[7]=f2bf(c[3]);
    *(s8*)(xbf + (size_t)idx * 8) = v;
    return;
  }
  int t = idx - nx8;
  if (t < 196608) {
    wqkv[t] = f2bf(qkv_w[t]);
  } else if (t < 262144) {
    int u = t - 196608;
    wproj[u] = f2bf(proj_w[u]);
  } else {
    int u = t - 262144;                 // [0, 32768): h*4096 + i*64 + j
    int h = u >> 12, i = (u >> 6) & 63, j = u & 63;
    int ridx = ((i >> 3) - (j >> 3) + 7) * 15 + ((i & 7) - (j & 7) + 7);
    biasf[u] = table[ridx * 8 + h];
  }
}

// ---------------- fused window attention ----------------
// Per-wave LDS (no cooperative staging -> no intra-round barriers):
//   QKs [64][72] shorts : cols 0-31 = Q, 32-63 = K, 64-71 pad (row 144B, 16B-aligned)
//   Vt  [32][68] shorts : Vt[d][tok], row 136B (b64 reads only)
//   Ps  overlays QKs    : [64][72] (P[i][j], j 0-63)
// per-wave = 9216 + 4352 = 13568 B; block = 54272 B -> 3 blocks/CU.
#define LDQK 72
#define LDV  68
#define LDP  72
#define LDO  264   // Olds rows (256 data + 8 pad)
#define WAVE_LDS 13568

// XB=1: x already bf16 in workspace. XB=0: fallback fp32 path.
template<int XB>
__global__ __launch_bounds__(256, 3) void fused_kernel(
    const void* __restrict__ xv, const float* __restrict__ mask,
    const float* __restrict__ qkv_b, const float* __restrict__ proj_b,
    const short* __restrict__ wqkv, const short* __restrict__ wproj,
    const float* __restrict__ biasf, float* __restrict__ out)
{
  __shared__ __align__(16) char smem[54272];
  const int tid  = threadIdx.x;
  const int lane = tid & 63;
  const int wv   = tid >> 6;          // wave 0..3
  const int m16  = lane & 15;
  const int quad = lane >> 4;
  const int b    = blockIdx.x;

  short* QKs = (short*)(smem + wv * WAVE_LDS);              // [64][72]
  short* Vt  = QKs + 4608;                                  // [32][68]
  short* Ps  = QKs;                                         // [64][72] overlay

  s4 opack[2][2][4];                                        // O in bf16 [round][td][ti]
  const float scale = 0.17677669529663687f;                 // 32^-0.5

  #pragma unroll            // MUST unroll: opack[rnd] needs compile-time index (no scratch)
  for (int rnd = 0; rnd < 2; ++rnd) {
    const int h = wv + rnd * 4;

    // ---- qkv GEMM for head h ----
    f4 acc[3][2][4];
    #pragma unroll
    for (int s = 0; s < 3; ++s)
      #pragma unroll
      for (int tn = 0; tn < 2; ++tn)
        #pragma unroll
        for (int ti = 0; ti < 4; ++ti) acc[s][tn][ti] = f4zero();

    #pragma unroll
    for (int ks = 0; ks < 8; ++ks) {
      s8 af[4];
      #pragma unroll
      for (int ti = 0; ti < 4; ++ti) {
        if constexpr (XB) {
          const short* xg = (const short*)xv + (size_t)b * 16384;
          af[ti] = *(const s8*)&xg[(m16 + 16*ti) * 256 + ks*32 + quad*8];
        } else {
          const float* xg = (const float*)xv + (size_t)b * 16384;
          const float* sp = xg + (m16 + 16*ti) * 256 + ks*32 + quad*8;
          f4 a = *(const f4*)sp;
          f4 c = *(const f4*)(sp + 4);
          s8 v;
          v[0]=f2bf(a[0]); v[1]=f2bf(a[1]); v[2]=f2bf(a[2]); v[3]=f2bf(a[3]);
          v[4]=f2bf(c[0]); v[5]=f2bf(c[1]); v[6]=f2bf(c[2]); v[7]=f2bf(c[3]);
          af[ti] = v;
        }
      }
      #pragma unroll
      for (int s = 0; s < 3; ++s)
        #pragma unroll
        for (int tn = 0; tn < 2; ++tn) {
          const s8 bf = *(const s8*)&wqkv[(size_t)(s*256 + h*32 + tn*16 + m16) * 256 + ks*32 + quad*8];
          #pragma unroll
          for (int ti = 0; ti < 4; ++ti)
            // s<2 swapped (W as A): D[d in quad*4+p][token in m16] -> d-contiguous LDS writes.
            // s=2 unswapped: D[token in quad*4+p][d in m16] -> Vt token-contiguous writes.
            acc[s][tn][ti] = (s < 2) ? MFMA16(bf, af[ti], acc[s][tn][ti])
                                     : MFMA16(af[ti], bf, acc[s][tn][ti]);
        }
    }

    // ---- epilogue: +bias, q*=scale; all LDS writes are b64 ----
    #pragma unroll
    for (int tn = 0; tn < 2; ++tn) {
      f4 bq = *(const f4*)&qkv_b[0*256 + h*32 + tn*16 + quad*4];
      f4 bk = *(const f4*)&qkv_b[1*256 + h*32 + tn*16 + quad*4];
      float bv = qkv_b[2*256 + h*32 + tn*16 + m16];
      #pragma unroll
      for (int ti = 0; ti < 4; ++ti) {
        f4 vq = (acc[0][tn][ti] + bq) * scale;
        f4 vk =  acc[1][tn][ti] + bk;
        s4 q4; q4[0]=f2bf(vq[0]); q4[1]=f2bf(vq[1]); q4[2]=f2bf(vq[2]); q4[3]=f2bf(vq[3]);
        s4 k4; k4[0]=f2bf(vk[0]); k4[1]=f2bf(vk[1]); k4[2]=f2bf(vk[2]); k4[3]=f2bf(vk[3]);
        *(s4*)&QKs[(ti*16 + m16)*LDQK + tn*16 + quad*4] = q4;        // Q cols 0-31
        *(s4*)&QKs[(ti*16 + m16)*LDQK + 32 + tn*16 + quad*4] = k4;   // K cols 32-63
        f4 vv = acc[2][tn][ti] + bv;
        s4 v4; v4[0]=f2bf(vv[0]); v4[1]=f2bf(vv[1]); v4[2]=f2bf(vv[2]); v4[3]=f2bf(vv[3]);
        *(s4*)&Vt[(tn*16 + m16)*LDV + ti*16 + quad*4] = v4;          // Vt[d][tok]
      }
    }
    wave_fence();

    // ---- S^T = K * Q^T (NT trick: both frags row-major [tok][d]) ----
    s8 qf[4], kf[4];
    #pragma unroll
    for (int t = 0; t < 4; ++t) {
      qf[t] = *(const s8*)&QKs[(m16 + 16*t) * LDQK + quad*8];
      kf[t] = *(const s8*)&QKs[(m16 + 16*t) * LDQK + 32 + quad*8];
    }
    f4 st[4][4];   // st[tjr][tic][p] = S[i=tic*16+m16][j=tjr*16+quad*4+p]
    #pragma unroll
    for (int tjr = 0; tjr < 4; ++tjr)
      #pragma unroll
      for (int tic = 0; tic < 4; ++tic)
        st[tjr][tic] = MFMA16(kf[tjr], qf[tic], f4zero());

    // bias + mask (float4 loads, j-contiguous thanks to S^T layout)
    const float* maskw = mask + (size_t)(b & 63) * 4096;
    #pragma unroll
    for (int tic = 0; tic < 4; ++tic) {
      int i = tic*16 + m16;
      #pragma unroll
      for (int tjr = 0; tjr < 4; ++tjr) {
        int j0 = tjr*16 + quad*4;
        f4 bb = *(const f4*)&biasf[(h*64 + i)*64 + j0];
        f4 mm = *(const f4*)&maskw[i*64 + j0];
        st[tjr][tic] += bb + mm;
      }
    }

    // ---- softmax over j (16 local values + xor16 + xor32) ----
    float linv[4];
    #pragma unroll
    for (int tic = 0; tic < 4; ++tic) {
      float mx = -1e30f;
      #pragma unroll
      for (int tjr = 0; tjr < 4; ++tjr)
        #pragma unroll
        for (int p = 0; p < 4; ++p) mx = fmaxf(mx, st[tjr][tic][p]);
      mx = fmaxf(mx, __shfl_xor(mx, 16, 64));
      mx = fmaxf(mx, __shfl_xor(mx, 32, 64));
      float sum = 0.f;
      #pragma unroll
      for (int tjr = 0; tjr < 4; ++tjr)
        #pragma unroll
        for (int p = 0; p < 4; ++p) {
          float e = exp2f((st[tjr][tic][p] - mx) * 1.4426950408889634f);
          st[tjr][tic][p] = e;
          sum += e;
        }
      sum += __shfl_xor(sum, 16, 64);
      sum += __shfl_xor(sum, 32, 64);
      linv[tic] = 1.f / sum;
    }

    // ---- write P (unnormalized exp) to LDS, b64-packed (overlay on QKs) ----
    #pragma unroll
    for (int tic = 0; tic < 4; ++tic) {
      int i = tic*16 + m16;
      #pragma unroll
      for (int tjr = 0; tjr < 4; ++tjr) {
        int j0 = tjr*16 + quad*4;
        s4 pv;
        pv[0]=f2bf(st[tjr][tic][0]); pv[1]=f2bf(st[tjr][tic][1]);
        pv[2]=f2bf(st[tjr][tic][2]); pv[3]=f2bf(st[tjr][tic][3]);
        *(s4*)&Ps[i*LDP + j0] = pv;
      }
    }
    wave_fence();

    // ---- O^T = Vt * P^T ----
    s8 vtf[2][2], pf[4][2];
    #pragma unroll
    for (int td = 0; td < 2; ++td)
      #pragma unroll
      for (int kk = 0; kk < 2; ++kk) {
        // Vt rows are 136B (8B-aligned) -> two ds_read_b64, not one b128
        s4 lo = *(const s4*)&Vt[(m16 + 16*td)*LDV + kk*32 + quad*8];
        s4 hi = *(const s4*)&Vt[(m16 + 16*td)*LDV + kk*32 + quad*8 + 4];
        vtf[td][kk] = s8cat(lo, hi);
      }
    #pragma unroll
    for (int ti = 0; ti < 4; ++ti)
      #pragma unroll
      for (int kk = 0; kk < 2; ++kk)
        pf[ti][kk] = *(const s8*)&Ps[(m16 + 16*ti)*LDP + kk*32 + quad*8];
    #pragma unroll
    for (int td = 0; td < 2; ++td)
      #pragma unroll
      for (int ti = 0; ti < 4; ++ti) {
        f4 o = MFMA16(vtf[td][0], pf[ti][0], f4zero());
        o = MFMA16(vtf[td][1], pf[ti][1], o);
        float li = linv[ti];
        s4 ov;
        ov[0]=f2bf(o[0]*li); ov[1]=f2bf(o[1]*li);
        ov[2]=f2bf(o[2]*li); ov[3]=f2bf(o[3]*li);
        opack[rnd][td][ti] = ov;                 // bf16-packed: halves live regs
      }
  } // rounds

  // ---- gather all heads' O into shared Olds [64][256] bf16 ----
  __syncthreads();                       // Olds overlays per-wave areas
  short* Olds = (short*)smem;
  #pragma unroll
  for (int rnd = 0; rnd < 2; ++rnd) {
    int h = wv + rnd*4;
    #pragma unroll
    for (int td = 0; td < 2; ++td)
      #pragma unroll
      for (int ti = 0; ti < 4; ++ti) {
        int i  = m16 + 16*ti;
        int d0 = h*32 + td*16 + quad*4;
        *(s4*)&Olds[i*LDO + d0] = opack[rnd][td][ti];
      }
  }
  __syncthreads();

  // ---- proj GEMM: out[64][256] = Olds * projW^T + proj_b (swapped -> f4 stores) ----
  f4 pacc[4][4];
  #pragma unroll
  for (int tn = 0; tn < 4; ++tn)
    #pragma unroll
    for (int ti = 0; ti < 4; ++ti) pacc[tn][ti] = f4zero();

  #pragma unroll
  for (int ks = 0; ks < 8; ++ks) {
    s8 af[4];
    #pragma unroll
    for (int ti = 0; ti < 4; ++ti)
      af[ti] = *(const s8*)&Olds[(m16 + 16*ti)*LDO + ks*32 + quad*8];
    #pragma unroll
    for (int tn = 0; tn < 4; ++tn) {
      const s8 bf = *(const s8*)&wproj[(size_t)(wv*64 + tn*16 + m16)*256 + ks*32 + quad*8];
      #pragma unroll
      for (int ti = 0; ti < 4; ++ti)
        pacc[tn][ti] = MFMA16(bf, af[ti], pacc[tn][ti]);   // D[c in quad*4+p][tok in m16]
    }
  }

  // ti-outer store order: each row's 4x64B chunks issue back-to-back (write combining)
  float* outb = out + (size_t)b * 16384;
  f4 pb[4];
  #pragma unroll
  for (int tn = 0; tn < 4; ++tn) pb[tn] = *(const f4*)&proj_b[wv*64 + tn*16 + quad*4];
  #pragma unroll
  for (int ti = 0; ti < 4; ++ti) {
    int i = ti*16 + m16;
    #pragma unroll
    for (int tn = 0; tn < 4; ++tn) {
      int c0 = wv*64 + tn*16 + quad*4;
      f4 v = pacc[tn][ti] + pb[tn];
      *(f4*)&outb[(size_t)i*256 + c0] = v;
    }
  }
}

extern "C" void kernel_launch(void* const* d_in, const int* in_sizes, int n_in,
                              void* d_out, int out_size, void* d_ws, size_t ws_size,
                              hipStream_t stream) {
  (void)in_sizes; (void)n_in; (void)out_size;
  const float* x      = (const float*)d_in[0];
  const float* mask   = (const float*)d_in[1];
  const float* qkv_w  = (const float*)d_in[2];
  const float* qkv_b  = (const float*)d_in[3];
  const float* proj_w = (const float*)d_in[4];
  const float* proj_b = (const float*)d_in[5];
  const float* table  = (const float*)d_in[6];
  // d_in[7] (rel_index) unused: index computed analytically (dtype-safe).
  float* out = (float*)d_out;

  const size_t XBF_BYTES = 134217728ull;     // 4096*64*256 bf16
  const size_t TAIL_BYTES = 655360ull;       // wqkv 384K + wproj 128K + biasf 128K
  char* ws = (char*)d_ws;

  if (ws_size >= XBF_BYTES + TAIL_BYTES) {
    short* xbf   = (short*)ws;
    short* wqkv  = (short*)(ws + XBF_BYTES);
    short* wproj = (short*)(ws + XBF_BYTES + 393216);
    float* biasf = (float*)(ws + XBF_BYTES + 524288);
    const int nx8 = 8388608;                 // 67.1M elems / 8 per thread
    prep_kernel<<<(nx8 + 294912) / 256, 256, 0, stream>>>(
        x, xbf, nx8, qkv_w, proj_w, table, wqkv, wproj, biasf);
    fused_kernel<1><<<4096, 256, 0, stream>>>(xbf, mask, qkv_b, proj_b, wqkv, wproj, biasf, out);
  } else {
    short* wqkv  = (short*)ws;
    short* wproj = (short*)(ws + 393216);
    float* biasf = (float*)(ws + 524288);
    prep_kernel<<<1152, 256, 0, stream>>>(
        x, (short*)nullptr, 0, qkv_w, proj_w, table, wqkv, wproj, biasf);
    fused_kernel<0><<<4096, 256, 0, stream>>>(x, mask, qkv_b, proj_b, wqkv, wproj, biasf, out);
  }
}

// Round 16
// 864.545 us; speedup vs baseline: 1.2630x; 1.2630x over previous
//
#include <hip/hip_runtime.h>
#include <hip/hip_bf16.h>

typedef __attribute__((ext_vector_type(4))) float  f4;
typedef __attribute__((ext_vector_type(8))) short  s8;
typedef __attribute__((ext_vector_type(4))) short  s4;

#define MFMA16(A,B,C) __builtin_amdgcn_mfma_f32_16x16x32_bf16((A),(B),(C),0,0,0)

// Native cast -> compiler emits v_cvt_pk_bf16_f32 for pairs (RNE).
__device__ __forceinline__ short f2bf(float f) {
  __hip_bfloat16 h = __float2bfloat16(f);
  return __builtin_bit_cast(short, h);
}

__device__ __forceinline__ f4 f4zero() { f4 z; z[0]=0.f; z[1]=0.f; z[2]=0.f; z[3]=0.f; return z; }

// Zero-cost fence: stops IR + MIR code motion across the LDS write->read handoff.
// DS pipe is in-order per wave, so no hardware wait is required for same-wave RAW.
__device__ __forceinline__ void wave_fence() {
  __builtin_amdgcn_wave_barrier();
  __builtin_amdgcn_sched_barrier(0);
}

// ---------------- prep: x/weight bf16 conversion + relative-position bias ----------------
__global__ __launch_bounds__(256) void prep_kernel(
    const float* __restrict__ x, short* __restrict__ xbf, int nx8,
    const float* __restrict__ qkv_w, const float* __restrict__ proj_w,
    const float* __restrict__ table,
    short* __restrict__ wqkv, short* __restrict__ wproj, float* __restrict__ biasf)
{
  int idx = blockIdx.x * 256 + threadIdx.x;
  if (idx < nx8) {
    const f4* src = (const f4*)(x + (size_t)idx * 8);
    f4 a = src[0], c = src[1];
    s8 v;
    v[0]=f2bf(a[0]); v[1]=f2bf(a[1]); v[2]=f2bf(a[2]); v[3]=f2bf(a[3]);
    v[4]=f2bf(c[0]); v[5]=f2bf(c[1]); v[6]=f2bf(c[2]); v[7]=f2bf(c[3]);
    *(s8*)(xbf + (size_t)idx * 8) = v;
    return;
  }
  int t = idx - nx8;
  if (t < 196608) {
    wqkv[t] = f2bf(qkv_w[t]);
  } else if (t < 262144) {
    int u = t - 196608;
    wproj[u] = f2bf(proj_w[u]);
  } else {
    int u = t - 262144;                 // [0, 32768): h*4096 + i*64 + j
    int h = u >> 12, i = (u >> 6) & 63, j = u & 63;
    int ridx = ((i >> 3) - (j >> 3) + 7) * 15 + ((i & 7) - (j & 7) + 7);
    biasf[u] = table[ridx * 8 + h];
  }
}

// ---------------- fused window attention ----------------
// LDS (59392 B/block, 2 blocks/CU):
//   per-wave (alive epilogue..PV): Qs[64][40] + Ks[64][40] + Vt[32][72] = 14848 B
//   Xs [64][264] bf16 (33792 B) TIME-OVERLAYS waves 0-2's areas: alive stage..gemm only.
//   Ps overlays Qs+Ks.
// Barriers: 3/round (restage guard, stage done, gemm done) + 2 for Olds = 8 total.
#define LDQ 40
#define LDV 72
#define LDP 72
#define LDX 264   // Xs row stride in shorts (528B: 4-dword bank shift/row -> <=2-way)
#define LDO 264   // Olds rows (256 data + 8 pad)
#define WAVE_LDS 14848

// XB=1: x already bf16 in workspace. XB=0: fallback fp32 path.
template<int XB>
__global__ __launch_bounds__(256, 2) void fused_kernel(
    const void* __restrict__ xv, const float* __restrict__ mask,
    const float* __restrict__ qkv_b, const float* __restrict__ proj_b,
    const short* __restrict__ wqkv, const short* __restrict__ wproj,
    const float* __restrict__ biasf, float* __restrict__ out)
{
  __shared__ __align__(16) char smem[59392];
  const int tid  = threadIdx.x;
  const int lane = tid & 63;
  const int wv   = tid >> 6;          // wave 0..3
  const int m16  = lane & 15;
  const int quad = lane >> 4;
  const int b    = blockIdx.x;

  short* Xs = (short*)smem;                                 // [64][264] overlay
  short* Qs = (short*)(smem + wv * WAVE_LDS);               // [64][40]
  short* Ks = Qs + 2560;                                    // [64][40]
  short* Vt = Ks + 2560;                                    // [32][72]
  short* Ps = Qs;                                           // [64][72] overlay

  s4 opack[2][2][4];                                        // O in bf16 [round][td][ti]
  const float scale = 0.17677669529663687f;                 // 32^-0.5

  // staging coords: thread t covers row r = t>>2, 64-short chunk q = t&3
  const int srow = tid >> 2;
  const int scol = (tid & 3) * 64;

  #pragma unroll            // MUST unroll: opack[rnd] needs compile-time index (no scratch)
  for (int rnd = 0; rnd < 2; ++rnd) {
    const int h = wv + rnd * 4;

    // ---- cooperative stage: x-tile -> Xs (one HBM latency exposure) ----
    __syncthreads();        // prior-round PV reads of Vt/Ps done before Xs overwrites
    {
      s8 v[8];
      if constexpr (XB) {
        const short* src = (const short*)xv + (size_t)b * 16384 + srow * 256 + scol;
        #pragma unroll
        for (int k = 0; k < 8; ++k) v[k] = *(const s8*)(src + k*8);
      } else {
        const float* src = (const float*)xv + (size_t)b * 16384 + srow * 256 + scol;
        #pragma unroll
        for (int k = 0; k < 8; ++k) {
          f4 a = *(const f4*)(src + k*8);
          f4 c = *(const f4*)(src + k*8 + 4);
          s8 w;
          w[0]=f2bf(a[0]); w[1]=f2bf(a[1]); w[2]=f2bf(a[2]); w[3]=f2bf(a[3]);
          w[4]=f2bf(c[0]); w[5]=f2bf(c[1]); w[6]=f2bf(c[2]); w[7]=f2bf(c[3]);
          v[k] = w;
        }
      }
      short* dst = &Xs[srow * LDX + scol];
      #pragma unroll
      for (int k = 0; k < 8; ++k) *(s8*)(dst + k*8) = v[k];
    }
    __syncthreads();        // Xs ready

    // ---- qkv GEMM for head h (af from LDS, bf from global L2-hot weights) ----
    f4 acc[3][2][4];
    #pragma unroll
    for (int s = 0; s < 3; ++s)
      #pragma unroll
      for (int tn = 0; tn < 2; ++tn)
        #pragma unroll
        for (int ti = 0; ti < 4; ++ti) acc[s][tn][ti] = f4zero();

    #pragma unroll
    for (int ks = 0; ks < 8; ++ks) {
      s8 af[4];
      #pragma unroll
      for (int ti = 0; ti < 4; ++ti)
        af[ti] = *(const s8*)&Xs[(m16 + 16*ti) * LDX + ks*32 + quad*8];
      #pragma unroll
      for (int s = 0; s < 3; ++s)
        #pragma unroll
        for (int tn = 0; tn < 2; ++tn) {
          const s8 bf = *(const s8*)&wqkv[(size_t)(s*256 + h*32 + tn*16 + m16) * 256 + ks*32 + quad*8];
          #pragma unroll
          for (int ti = 0; ti < 4; ++ti)
            // s<2 swapped (W as A): D[d in quad*4+p][token in m16] -> d-contiguous LDS writes.
            // s=2 unswapped: D[token in quad*4+p][d in m16] -> Vt token-contiguous writes.
            acc[s][tn][ti] = (s < 2) ? MFMA16(bf, af[ti], acc[s][tn][ti])
                                     : MFMA16(af[ti], bf, acc[s][tn][ti]);
        }
    }
    __syncthreads();        // all waves done reading Xs before epilogue overwrites it

    // ---- epilogue: +bias, q*=scale; all LDS writes are b64 ----
    #pragma unroll
    for (int tn = 0; tn < 2; ++tn) {
      f4 bq = *(const f4*)&qkv_b[0*256 + h*32 + tn*16 + quad*4];
      f4 bk = *(const f4*)&qkv_b[1*256 + h*32 + tn*16 + quad*4];
      float bv = qkv_b[2*256 + h*32 + tn*16 + m16];
      #pragma unroll
      for (int ti = 0; ti < 4; ++ti) {
        f4 vq = (acc[0][tn][ti] + bq) * scale;
        f4 vk =  acc[1][tn][ti] + bk;
        s4 q4; q4[0]=f2bf(vq[0]); q4[1]=f2bf(vq[1]); q4[2]=f2bf(vq[2]); q4[3]=f2bf(vq[3]);
        s4 k4; k4[0]=f2bf(vk[0]); k4[1]=f2bf(vk[1]); k4[2]=f2bf(vk[2]); k4[3]=f2bf(vk[3]);
        *(s4*)&Qs[(ti*16 + m16)*LDQ + tn*16 + quad*4] = q4;   // [tok][d]
        *(s4*)&Ks[(ti*16 + m16)*LDQ + tn*16 + quad*4] = k4;   // [tok][d]
        f4 vv = acc[2][tn][ti] + bv;
        s4 v4; v4[0]=f2bf(vv[0]); v4[1]=f2bf(vv[1]); v4[2]=f2bf(vv[2]); v4[3]=f2bf(vv[3]);
        *(s4*)&Vt[(tn*16 + m16)*LDV + ti*16 + quad*4] = v4;   // Vt[d][tok]
      }
    }
    wave_fence();

    // ---- S^T = K * Q^T (NT trick: both frags row-major [tok][d]) ----
    s8 qf[4], kf[4];
    #pragma unroll
    for (int t = 0; t < 4; ++t) {
      qf[t] = *(const s8*)&Qs[(m16 + 16*t) * LDQ + quad*8];
      kf[t] = *(const s8*)&Ks[(m16 + 16*t) * LDQ + quad*8];
    }
    f4 st[4][4];   // st[tjr][tic][p] = S[i=tic*16+m16][j=tjr*16+quad*4+p]
    #pragma unroll
    for (int tjr = 0; tjr < 4; ++tjr)
      #pragma unroll
      for (int tic = 0; tic < 4; ++tic)
        st[tjr][tic] = MFMA16(kf[tjr], qf[tic], f4zero());

    // bias + mask (float4 loads, j-contiguous thanks to S^T layout)
    const float* maskw = mask + (size_t)(b & 63) * 4096;
    #pragma unroll
    for (int tic = 0; tic < 4; ++tic) {
      int i = tic*16 + m16;
      #pragma unroll
      for (int tjr = 0; tjr < 4; ++tjr) {
        int j0 = tjr*16 + quad*4;
        f4 bb = *(const f4*)&biasf[(h*64 + i)*64 + j0];
        f4 mm = *(const f4*)&maskw[i*64 + j0];
        st[tjr][tic] += bb + mm;
      }
    }

    // ---- softmax over j (16 local values + xor16 + xor32) ----
    float linv[4];
    #pragma unroll
    for (int tic = 0; tic < 4; ++tic) {
      float mx = -1e30f;
      #pragma unroll
      for (int tjr = 0; tjr < 4; ++tjr)
        #pragma unroll
        for (int p = 0; p < 4; ++p) mx = fmaxf(mx, st[tjr][tic][p]);
      mx = fmaxf(mx, __shfl_xor(mx, 16, 64));
      mx = fmaxf(mx, __shfl_xor(mx, 32, 64));
      float sum = 0.f;
      #pragma unroll
      for (int tjr = 0; tjr < 4; ++tjr)
        #pragma unroll
        for (int p = 0; p < 4; ++p) {
          float e = exp2f((st[tjr][tic][p] - mx) * 1.4426950408889634f);
          st[tjr][tic][p] = e;
          sum += e;
        }
      sum += __shfl_xor(sum, 16, 64);
      sum += __shfl_xor(sum, 32, 64);
      linv[tic] = 1.f / sum;
    }

    // ---- write P (unnormalized exp) to LDS, b64-packed (overlay on Qs/Ks) ----
    #pragma unroll
    for (int tic = 0; tic < 4; ++tic) {
      int i = tic*16 + m16;
      #pragma unroll
      for (int tjr = 0; tjr < 4; ++tjr) {
        int j0 = tjr*16 + quad*4;
        s4 pv;
        pv[0]=f2bf(st[tjr][tic][0]); pv[1]=f2bf(st[tjr][tic][1]);
        pv[2]=f2bf(st[tjr][tic][2]); pv[3]=f2bf(st[tjr][tic][3]);
        *(s4*)&Ps[i*LDP + j0] = pv;
      }
    }
    wave_fence();

    // ---- O^T = Vt * P^T ----
    s8 vtf[2][2], pf[4][2];
    #pragma unroll
    for (int td = 0; td < 2; ++td)
      #pragma unroll
      for (int kk = 0; kk < 2; ++kk)
        vtf[td][kk] = *(const s8*)&Vt[(m16 + 16*td)*LDV + kk*32 + quad*8];
    #pragma unroll
    for (int ti = 0; ti < 4; ++ti)
      #pragma unroll
      for (int kk = 0; kk < 2; ++kk)
        pf[ti][kk] = *(const s8*)&Ps[(m16 + 16*ti)*LDP + kk*32 + quad*8];
    #pragma unroll
    for (int td = 0; td < 2; ++td)
      #pragma unroll
      for (int ti = 0; ti < 4; ++ti) {
        f4 o = MFMA16(vtf[td][0], pf[ti][0], f4zero());
        o = MFMA16(vtf[td][1], pf[ti][1], o);
        float li = linv[ti];
        s4 ov;
        ov[0]=f2bf(o[0]*li); ov[1]=f2bf(o[1]*li);
        ov[2]=f2bf(o[2]*li); ov[3]=f2bf(o[3]*li);
        opack[rnd][td][ti] = ov;                 // bf16-packed: halves live regs
      }
  } // rounds

  // ---- gather all heads' O into shared Olds [64][256] bf16 ----
  __syncthreads();                       // Olds overlays per-wave areas
  short* Olds = (short*)smem;
  #pragma unroll
  for (int rnd = 0; rnd < 2; ++rnd) {
    int h = wv + rnd*4;
    #pragma unroll
    for (int td = 0; td < 2; ++td)
      #pragma unroll
      for (int ti = 0; ti < 4; ++ti) {
        int i  = m16 + 16*ti;
        int d0 = h*32 + td*16 + quad*4;
        *(s4*)&Olds[i*LDO + d0] = opack[rnd][td][ti];
      }
  }
  __syncthreads();

  // ---- proj GEMM: out[64][256] = Olds * projW^T + proj_b (swapped -> f4 stores) ----
  f4 pacc[4][4];
  #pragma unroll
  for (int tn = 0; tn < 4; ++tn)
    #pragma unroll
    for (int ti = 0; ti < 4; ++ti) pacc[tn][ti] = f4zero();

  #pragma unroll
  for (int ks = 0; ks < 8; ++ks) {
    s8 af[4];
    #pragma unroll
    for (int ti = 0; ti < 4; ++ti)
      af[ti] = *(const s8*)&Olds[(m16 + 16*ti)*LDO + ks*32 + quad*8];
    #pragma unroll
    for (int tn = 0; tn < 4; ++tn) {
      const s8 bf = *(const s8*)&wproj[(size_t)(wv*64 + tn*16 + m16)*256 + ks*32 + quad*8];
      #pragma unroll
      for (int ti = 0; ti < 4; ++ti)
        pacc[tn][ti] = MFMA16(bf, af[ti], pacc[tn][ti]);   // D[c in quad*4+p][tok in m16]
    }
  }

  // ti-outer store order: each row's 4x64B chunks issue back-to-back (write combining)
  float* outb = out + (size_t)b * 16384;
  f4 pb[4];
  #pragma unroll
  for (int tn = 0; tn < 4; ++tn) pb[tn] = *(const f4*)&proj_b[wv*64 + tn*16 + quad*4];
  #pragma unroll
  for (int ti = 0; ti < 4; ++ti) {
    int i = ti*16 + m16;
    #pragma unroll
    for (int tn = 0; tn < 4; ++tn) {
      int c0 = wv*64 + tn*16 + quad*4;
      f4 v = pacc[tn][ti] + pb[tn];
      *(f4*)&outb[(size_t)i*256 + c0] = v;
    }
  }
}

extern "C" void kernel_launch(void* const* d_in, const int* in_sizes, int n_in,
                              void* d_out, int out_size, void* d_ws, size_t ws_size,
                              hipStream_t stream) {
  (void)in_sizes; (void)n_in; (void)out_size;
  const float* x      = (const float*)d_in[0];
  const float* mask   = (const float*)d_in[1];
  const float* qkv_w  = (const float*)d_in[2];
  const float* qkv_b  = (const float*)d_in[3];
  const float* proj_w = (const float*)d_in[4];
  const float* proj_b = (const float*)d_in[5];
  const float* table  = (const float*)d_in[6];
  // d_in[7] (rel_index) unused: index computed analytically (dtype-safe).
  float* out = (float*)d_out;

  const size_t XBF_BYTES = 134217728ull;     // 4096*64*256 bf16
  const size_t TAIL_BYTES = 655360ull;       // wqkv 384K + wproj 128K + biasf 128K
  char* ws = (char*)d_ws;

  if (ws_size >= XBF_BYTES + TAIL_BYTES) {
    short* xbf   = (short*)ws;
    short* wqkv  = (short*)(ws + XBF_BYTES);
    short* wproj = (short*)(ws + XBF_BYTES + 393216);
    float* biasf = (float*)(ws + XBF_BYTES + 524288);
    const int nx8 = 8388608;                 // 67.1M elems / 8 per thread
    prep_kernel<<<(nx8 + 294912) / 256, 256, 0, stream>>>(
        x, xbf, nx8, qkv_w, proj_w, table, wqkv, wproj, biasf);
    fused_kernel<1><<<4096, 256, 0, stream>>>(xbf, mask, qkv_b, proj_b, wqkv, wproj, biasf, out);
  } else {
    short* wqkv  = (short*)ws;
    short* wproj = (short*)(ws + 393216);
    float* biasf = (float*)(ws + 524288);
    prep_kernel<<<1152, 256, 0, stream>>>(
        x, (short*)nullptr, 0, qkv_w, proj_w, table, wqkv, wproj, biasf);
    fused_kernel<0><<<4096, 256, 0, stream>>>(x, mask, qkv_b, proj_b, wqkv, wproj, biasf, out);
  }
}

// Round 17
// 864.117 us; speedup vs baseline: 1.2636x; 1.0005x over previous
//
#include <hip/hip_runtime.h>
#include <hip/hip_bf16.h>

typedef __attribute__((ext_vector_type(4))) float  f4;
typedef __attribute__((ext_vector_type(8))) short  s8;
typedef __attribute__((ext_vector_type(4))) short  s4;

#define MFMA16(A,B,C) __builtin_amdgcn_mfma_f32_16x16x32_bf16((A),(B),(C),0,0,0)

// Native cast -> compiler emits v_cvt_pk_bf16_f32 for pairs (RNE).
__device__ __forceinline__ short f2bf(float f) {
  __hip_bfloat16 h = __float2bfloat16(f);
  return __builtin_bit_cast(short, h);
}

__device__ __forceinline__ f4 f4zero() { f4 z; z[0]=0.f; z[1]=0.f; z[2]=0.f; z[3]=0.f; return z; }

__device__ __forceinline__ s8 s8cat(s4 a, s4 b) {
  s8 r; r[0]=a[0]; r[1]=a[1]; r[2]=a[2]; r[3]=a[3];
       r[4]=b[0]; r[5]=b[1]; r[6]=b[2]; r[7]=b[3]; return r;
}

// Zero-cost fence: stops IR + MIR code motion across the LDS write->read handoff.
// DS pipe is in-order per wave, so no hardware wait is required for same-wave RAW.
__device__ __forceinline__ void wave_fence() {
  __builtin_amdgcn_wave_barrier();
  __builtin_amdgcn_sched_barrier(0);
}

// ---------------- prep: x/weight bf16 conversion + relative-position bias ----------------
__global__ __launch_bounds__(256) void prep_kernel(
    const float* __restrict__ x, short* __restrict__ xbf, int nx8,
    const float* __restrict__ qkv_w, const float* __restrict__ proj_w,
    const float* __restrict__ table,
    short* __restrict__ wqkv, short* __restrict__ wproj, float* __restrict__ biasf)
{
  int idx = blockIdx.x * 256 + threadIdx.x;
  if (idx < nx8) {
    const f4* src = (const f4*)(x + (size_t)idx * 8);
    f4 a = src[0], c = src[1];
    s8 v;
    v[0]=f2bf(a[0]); v[1]=f2bf(a[1]); v[2]=f2bf(a[2]); v[3]=f2bf(a[3]);
    v[4]=f2bf(c[0]); v[5]=f2bf(c[1]); v[6]=f2bf(c[2]); v[7]=f2bf(c[3]);
    *(s8*)(xbf + (size_t)idx * 8) = v;
    return;
  }
  int t = idx - nx8;
  if (t < 196608) {
    wqkv[t] = f2bf(qkv_w[t]);
  } else if (t < 262144) {
    int u = t - 196608;
    wproj[u] = f2bf(proj_w[u]);
  } else {
    int u = t - 262144;                 // [0, 32768): h*4096 + i*64 + j
    int h = u >> 12, i = (u >> 6) & 63, j = u & 63;
    int ridx = ((i >> 3) - (j >> 3) + 7) * 15 + ((i & 7) - (j & 7) + 7);
    biasf[u] = table[ridx * 8 + h];
  }
}

// ---------------- fused window attention ----------------
// LDS 54272 B/block -> floor(163840/54272) = 3 blocks/CU (12 waves, ~37% occ).
// VGPR stays compiler-chosen (~128) under (256,2): 3 waves/SIMD x 128 = 384 <= 512. No spills.
//   per-wave (alive epilogue..PV): QKs[64][72] (Q cols 0-31, K cols 32-63, pad 64-71;
//     row 144B, 16B-aligned) + Vt[32][68] (row 136B, b64 accesses) = 13568 B
//   Xs [64][264] bf16 (33792 B) TIME-OVERLAYS waves 0-2's areas (3x13568=40704 >= 33792):
//     alive stage..gemm only.  Ps [64][72] overlays QKs.
// Barriers: 3/round + 2 for Olds = 8 total.
#define LDQK 72
#define LDV  68
#define LDP  72
#define LDX  264  // Xs row stride in shorts (528B: 4-dword bank shift/row -> low conflict)
#define LDO  264  // Olds rows (256 data + 8 pad)
#define WAVE_LDS 13568

// XB=1: x already bf16 in workspace. XB=0: fallback fp32 path.
template<int XB>
__global__ __launch_bounds__(256, 2) void fused_kernel(
    const void* __restrict__ xv, const float* __restrict__ mask,
    const float* __restrict__ qkv_b, const float* __restrict__ proj_b,
    const short* __restrict__ wqkv, const short* __restrict__ wproj,
    const float* __restrict__ biasf, float* __restrict__ out)
{
  __shared__ __align__(16) char smem[54272];
  const int tid  = threadIdx.x;
  const int lane = tid & 63;
  const int wv   = tid >> 6;          // wave 0..3
  const int m16  = lane & 15;
  const int quad = lane >> 4;
  const int b    = blockIdx.x;

  short* Xs  = (short*)smem;                                // [64][264] overlay (waves 0-2)
  short* QKs = (short*)(smem + wv * WAVE_LDS);              // [64][72]
  short* Vt  = QKs + 4608;                                  // [32][68]
  short* Ps  = QKs;                                         // [64][72] overlay

  s4 opack[2][2][4];                                        // O in bf16 [round][td][ti]
  const float scale = 0.17677669529663687f;                 // 32^-0.5

  // staging coords: thread t covers row r = t>>2, 64-short chunk q = t&3
  const int srow = tid >> 2;
  const int scol = (tid & 3) * 64;

  #pragma unroll            // MUST unroll: opack[rnd] needs compile-time index (no scratch)
  for (int rnd = 0; rnd < 2; ++rnd) {
    const int h = wv + rnd * 4;

    // ---- cooperative stage: x-tile -> Xs (one HBM latency exposure) ----
    __syncthreads();        // prior-round PV reads of Vt/Ps done before Xs overwrites
    {
      s8 v[8];
      if constexpr (XB) {
        const short* src = (const short*)xv + (size_t)b * 16384 + srow * 256 + scol;
        #pragma unroll
        for (int k = 0; k < 8; ++k) v[k] = *(const s8*)(src + k*8);
      } else {
        const float* src = (const float*)xv + (size_t)b * 16384 + srow * 256 + scol;
        #pragma unroll
        for (int k = 0; k < 8; ++k) {
          f4 a = *(const f4*)(src + k*8);
          f4 c = *(const f4*)(src + k*8 + 4);
          s8 w;
          w[0]=f2bf(a[0]); w[1]=f2bf(a[1]); w[2]=f2bf(a[2]); w[3]=f2bf(a[3]);
          w[4]=f2bf(c[0]); w[5]=f2bf(c[1]); w[6]=f2bf(c[2]); w[7]=f2bf(c[3]);
          v[k] = w;
        }
      }
      short* dst = &Xs[srow * LDX + scol];
      #pragma unroll
      for (int k = 0; k < 8; ++k) *(s8*)(dst + k*8) = v[k];
    }
    __syncthreads();        // Xs ready

    // ---- qkv GEMM for head h (af from LDS, bf from global L2-hot weights) ----
    f4 acc[3][2][4];
    #pragma unroll
    for (int s = 0; s < 3; ++s)
      #pragma unroll
      for (int tn = 0; tn < 2; ++tn)
        #pragma unroll
        for (int ti = 0; ti < 4; ++ti) acc[s][tn][ti] = f4zero();

    #pragma unroll
    for (int ks = 0; ks < 8; ++ks) {
      s8 af[4];
      #pragma unroll
      for (int ti = 0; ti < 4; ++ti)
        af[ti] = *(const s8*)&Xs[(m16 + 16*ti) * LDX + ks*32 + quad*8];
      #pragma unroll
      for (int s = 0; s < 3; ++s)
        #pragma unroll
        for (int tn = 0; tn < 2; ++tn) {
          const s8 bf = *(const s8*)&wqkv[(size_t)(s*256 + h*32 + tn*16 + m16) * 256 + ks*32 + quad*8];
          #pragma unroll
          for (int ti = 0; ti < 4; ++ti)
            // s<2 swapped (W as A): D[d in quad*4+p][token in m16] -> d-contiguous LDS writes.
            // s=2 unswapped: D[token in quad*4+p][d in m16] -> Vt token-contiguous writes.
            acc[s][tn][ti] = (s < 2) ? MFMA16(bf, af[ti], acc[s][tn][ti])
                                     : MFMA16(af[ti], bf, acc[s][tn][ti]);
        }
    }
    __syncthreads();        // all waves done reading Xs before epilogue overwrites it

    // ---- epilogue: +bias, q*=scale; all LDS writes are b64 ----
    #pragma unroll
    for (int tn = 0; tn < 2; ++tn) {
      f4 bq = *(const f4*)&qkv_b[0*256 + h*32 + tn*16 + quad*4];
      f4 bk = *(const f4*)&qkv_b[1*256 + h*32 + tn*16 + quad*4];
      float bv = qkv_b[2*256 + h*32 + tn*16 + m16];
      #pragma unroll
      for (int ti = 0; ti < 4; ++ti) {
        f4 vq = (acc[0][tn][ti] + bq) * scale;
        f4 vk =  acc[1][tn][ti] + bk;
        s4 q4; q4[0]=f2bf(vq[0]); q4[1]=f2bf(vq[1]); q4[2]=f2bf(vq[2]); q4[3]=f2bf(vq[3]);
        s4 k4; k4[0]=f2bf(vk[0]); k4[1]=f2bf(vk[1]); k4[2]=f2bf(vk[2]); k4[3]=f2bf(vk[3]);
        *(s4*)&QKs[(ti*16 + m16)*LDQK + tn*16 + quad*4] = q4;        // Q cols 0-31
        *(s4*)&QKs[(ti*16 + m16)*LDQK + 32 + tn*16 + quad*4] = k4;   // K cols 32-63
        f4 vv = acc[2][tn][ti] + bv;
        s4 v4; v4[0]=f2bf(vv[0]); v4[1]=f2bf(vv[1]); v4[2]=f2bf(vv[2]); v4[3]=f2bf(vv[3]);
        *(s4*)&Vt[(tn*16 + m16)*LDV + ti*16 + quad*4] = v4;          // Vt[d][tok]
      }
    }
    wave_fence();

    // ---- S^T = K * Q^T (NT trick: both frags row-major [tok][d]) ----
    s8 qf[4], kf[4];
    #pragma unroll
    for (int t = 0; t < 4; ++t) {
      qf[t] = *(const s8*)&QKs[(m16 + 16*t) * LDQK + quad*8];
      kf[t] = *(const s8*)&QKs[(m16 + 16*t) * LDQK + 32 + quad*8];
    }
    f4 st[4][4];   // st[tjr][tic][p] = S[i=tic*16+m16][j=tjr*16+quad*4+p]
    #pragma unroll
    for (int tjr = 0; tjr < 4; ++tjr)
      #pragma unroll
      for (int tic = 0; tic < 4; ++tic)
        st[tjr][tic] = MFMA16(kf[tjr], qf[tic], f4zero());

    // bias + mask (float4 loads, j-contiguous thanks to S^T layout)
    const float* maskw = mask + (size_t)(b & 63) * 4096;
    #pragma unroll
    for (int tic = 0; tic < 4; ++tic) {
      int i = tic*16 + m16;
      #pragma unroll
      for (int tjr = 0; tjr < 4; ++tjr) {
        int j0 = tjr*16 + quad*4;
        f4 bb = *(const f4*)&biasf[(h*64 + i)*64 + j0];
        f4 mm = *(const f4*)&maskw[i*64 + j0];
        st[tjr][tic] += bb + mm;
      }
    }

    // ---- softmax over j (16 local values + xor16 + xor32) ----
    float linv[4];
    #pragma unroll
    for (int tic = 0; tic < 4; ++tic) {
      float mx = -1e30f;
      #pragma unroll
      for (int tjr = 0; tjr < 4; ++tjr)
        #pragma unroll
        for (int p = 0; p < 4; ++p) mx = fmaxf(mx, st[tjr][tic][p]);
      mx = fmaxf(mx, __shfl_xor(mx, 16, 64));
      mx = fmaxf(mx, __shfl_xor(mx, 32, 64));
      float sum = 0.f;
      #pragma unroll
      for (int tjr = 0; tjr < 4; ++tjr)
        #pragma unroll
        for (int p = 0; p < 4; ++p) {
          float e = exp2f((st[tjr][tic][p] - mx) * 1.4426950408889634f);
          st[tjr][tic][p] = e;
          sum += e;
        }
      sum += __shfl_xor(sum, 16, 64);
      sum += __shfl_xor(sum, 32, 64);
      linv[tic] = 1.f / sum;
    }

    // ---- write P (unnormalized exp) to LDS, b64-packed (overlay on QKs) ----
    #pragma unroll
    for (int tic = 0; tic < 4; ++tic) {
      int i = tic*16 + m16;
      #pragma unroll
      for (int tjr = 0; tjr < 4; ++tjr) {
        int j0 = tjr*16 + quad*4;
        s4 pv;
        pv[0]=f2bf(st[tjr][tic][0]); pv[1]=f2bf(st[tjr][tic][1]);
        pv[2]=f2bf(st[tjr][tic][2]); pv[3]=f2bf(st[tjr][tic][3]);
        *(s4*)&Ps[i*LDP + j0] = pv;
      }
    }
    wave_fence();

    // ---- O^T = Vt * P^T ----
    s8 vtf[2][2], pf[4][2];
    #pragma unroll
    for (int td = 0; td < 2; ++td)
      #pragma unroll
      for (int kk = 0; kk < 2; ++kk) {
        // Vt rows are 136B (8B-aligned) -> two ds_read_b64, not one b128
        s4 lo = *(const s4*)&Vt[(m16 + 16*td)*LDV + kk*32 + quad*8];
        s4 hi = *(const s4*)&Vt[(m16 + 16*td)*LDV + kk*32 + quad*8 + 4];
        vtf[td][kk] = s8cat(lo, hi);
      }
    #pragma unroll
    for (int ti = 0; ti < 4; ++ti)
      #pragma unroll
      for (int kk = 0; kk < 2; ++kk)
        pf[ti][kk] = *(const s8*)&Ps[(m16 + 16*ti)*LDP + kk*32 + quad*8];
    #pragma unroll
    for (int td = 0; td < 2; ++td)
      #pragma unroll
      for (int ti = 0; ti < 4; ++ti) {
        f4 o = MFMA16(vtf[td][0], pf[ti][0], f4zero());
        o = MFMA16(vtf[td][1], pf[ti][1], o);
        float li = linv[ti];
        s4 ov;
        ov[0]=f2bf(o[0]*li); ov[1]=f2bf(o[1]*li);
        ov[2]=f2bf(o[2]*li); ov[3]=f2bf(o[3]*li);
        opack[rnd][td][ti] = ov;                 // bf16-packed: halves live regs
      }
  } // rounds

  // ---- gather all heads' O into shared Olds [64][264] bf16 ----
  __syncthreads();                       // Olds overlays per-wave areas
  short* Olds = (short*)smem;
  #pragma unroll
  for (int rnd = 0; rnd < 2; ++rnd) {
    int h = wv + rnd*4;
    #pragma unroll
    for (int td = 0; td < 2; ++td)
      #pragma unroll
      for (int ti = 0; ti < 4; ++ti) {
        int i  = m16 + 16*ti;
        int d0 = h*32 + td*16 + quad*4;
        *(s4*)&Olds[i*LDO + d0] = opack[rnd][td][ti];
      }
  }
  __syncthreads();

  // ---- proj GEMM: out[64][256] = Olds * projW^T + proj_b (swapped -> f4 stores) ----
  f4 pacc[4][4];
  #pragma unroll
  for (int tn = 0; tn < 4; ++tn)
    #pragma unroll
    for (int ti = 0; ti < 4; ++ti) pacc[tn][ti] = f4zero();

  #pragma unroll
  for (int ks = 0; ks < 8; ++ks) {
    s8 af[4];
    #pragma unroll
    for (int ti = 0; ti < 4; ++ti)
      af[ti] = *(const s8*)&Olds[(m16 + 16*ti)*LDO + ks*32 + quad*8];
    #pragma unroll
    for (int tn = 0; tn < 4; ++tn) {
      const s8 bf = *(const s8*)&wproj[(size_t)(wv*64 + tn*16 + m16)*256 + ks*32 + quad*8];
      #pragma unroll
      for (int ti = 0; ti < 4; ++ti)
        pacc[tn][ti] = MFMA16(bf, af[ti], pacc[tn][ti]);   // D[c in quad*4+p][tok in m16]
    }
  }

  // ti-outer store order: each row's 4x64B chunks issue back-to-back (write combining)
  float* outb = out + (size_t)b * 16384;
  f4 pb[4];
  #pragma unroll
  for (int tn = 0; tn < 4; ++tn) pb[tn] = *(const f4*)&proj_b[wv*64 + tn*16 + quad*4];
  #pragma unroll
  for (int ti = 0; ti < 4; ++ti) {
    int i = ti*16 + m16;
    #pragma unroll
    for (int tn = 0; tn < 4; ++tn) {
      int c0 = wv*64 + tn*16 + quad*4;
      f4 v = pacc[tn][ti] + pb[tn];
      *(f4*)&outb[(size_t)i*256 + c0] = v;
    }
  }
}

extern "C" void kernel_launch(void* const* d_in, const int* in_sizes, int n_in,
                              void* d_out, int out_size, void* d_ws, size_t ws_size,
                              hipStream_t stream) {
  (void)in_sizes; (void)n_in; (void)out_size;
  const float* x      = (const float*)d_in[0];
  const float* mask   = (const float*)d_in[1];
  const float* qkv_w  = (const float*)d_in[2];
  const float* qkv_b  = (const float*)d_in[3];
  const float* proj_w = (const float*)d_in[4];
  const float* proj_b = (const float*)d_in[5];
  const float* table  = (const float*)d_in[6];
  // d_in[7] (rel_index) unused: index computed analytically (dtype-safe).
  float* out = (float*)d_out;

  const size_t XBF_BYTES = 134217728ull;     // 4096*64*256 bf16
  const size_t TAIL_BYTES = 655360ull;       // wqkv 384K + wproj 128K + biasf 128K
  char* ws = (char*)d_ws;

  if (ws_size >= XBF_BYTES + TAIL_BYTES) {
    short* xbf   = (short*)ws;
    short* wqkv  = (short*)(ws + XBF_BYTES);
    short* wproj = (short*)(ws + XBF_BYTES + 393216);
    float* biasf = (float*)(ws + XBF_BYTES + 524288);
    const int nx8 = 8388608;                 // 67.1M elems / 8 per thread
    prep_kernel<<<(nx8 + 294912) / 256, 256, 0, stream>>>(
        x, xbf, nx8, qkv_w, proj_w, table, wqkv, wproj, biasf);
    fused_kernel<1><<<4096, 256, 0, stream>>>(xbf, mask, qkv_b, proj_b, wqkv, wproj, biasf, out);
  } else {
    short* wqkv  = (short*)ws;
    short* wproj = (short*)(ws + 393216);
    float* biasf = (float*)(ws + 524288);
    prep_kernel<<<1152, 256, 0, stream>>>(
        x, (short*)nullptr, 0, qkv_w, proj_w, table, wqkv, wproj, biasf);
    fused_kernel<0><<<4096, 256, 0, stream>>>(x, mask, qkv_b, proj_b, wqkv, wproj, biasf, out);
  }
}